// Round 3
// baseline (227.393 us; speedup 1.0000x reference)
//
#include <hip/hip_runtime.h>

// CosineHammingLSH bucketed attention, MFMA bf16x3, zero-LDS-matrix version.
// S^T = K*Q^T via mfma_f32_32x32x16_bf16 (so S^T C/D layout == GEMM2 A-operand
// row layout); exp + bf16 hi/lo split in registers (v_cvt_pk_bf16_f32);
// cross-half redistribution via v_permlane32_swap_b32 (T12 pattern) instead of
// an LDS round-trip. LDS = 512B/wave (index tables only). One wave per bucket.

typedef __attribute__((ext_vector_type(8)))  short bf16x8;
typedef __attribute__((ext_vector_type(16))) float f32x16;

constexpr int Nc  = 4096;
constexpr int Dc  = 64;
constexpr int WPB = 4;   // waves (=buckets) per 256-thread block

union FragU { uint u[4]; bf16x8 v; };

__device__ __forceinline__ uint cvtpk(float a, float b) {
    uint r;
    asm("v_cvt_pk_bf16_f32 %0, %1, %2" : "=v"(r) : "v"(a), "v"(b));
    return r;  // low16 = bf16(a), high16 = bf16(b)
}
// Exchange d's upper 32 lanes with s's lower 32 lanes:
// d' = {d[0:31], s[0:31]}, s' = {d[32:63], s[32:63]}
__device__ __forceinline__ void plswap(uint& d, uint& s) {
    asm("v_permlane32_swap_b32 %0, %1" : "+&v"(d), "+&v"(s));
}
// split x0,x1 into packed bf16 hi word + packed bf16 residual-lo word
__device__ __forceinline__ void split2(float x0, float x1, uint& hp, uint& lp) {
    hp = cvtpk(x0, x1);
    const float h0 = __uint_as_float(hp << 16);
    const float h1 = __uint_as_float(hp & 0xffff0000u);
    lp = cvtpk(x0 - h0, x1 - h1);
}
__device__ __forceinline__ void load8split(const float* p, FragU& hi, FragU& lo) {
    const float4 a = *(const float4*)p;
    const float4 b = *(const float4*)(p + 4);
    split2(a.x, a.y, hi.u[0], lo.u[0]);
    split2(a.z, a.w, hi.u[1], lo.u[1]);
    split2(b.x, b.y, hi.u[2], lo.u[2]);
    split2(b.z, b.w, hi.u[3], lo.u[3]);
}
#define MFMA32(A, B, C) __builtin_amdgcn_mfma_f32_32x32x16_bf16((A), (B), (C), 0, 0, 0)

__global__ __launch_bounds__(WPB * 64, 3)
void lsh_mfma3(const float* __restrict__ Qg, const float* __restrict__ Kg,
               const float* __restrict__ Wg, const int* __restrict__ Kidx,
               const int* __restrict__ Qidx, float* __restrict__ Og, int nbuck)
{
    __shared__ int kposL[WPB][64];
    __shared__ int qposL[WPB][64];

    const int wv   = threadIdx.x >> 6;
    const int lane = threadIdx.x & 63;
    const int bucket = blockIdx.x * WPB + wv;
    if (bucket >= nbuck) return;                 // uniform; never taken at 4096/4

    const int bh  = bucket >> 6;
    const int blk = bucket & 63;
    const size_t base = (size_t)bh * (size_t)(Nc * Dc);
    const int ib  = bh * Nc + blk * 64;
    const int c32 = lane & 31;
    const int h   = lane >> 5;
    const int dh  = 8 * h;

    const int ki = Kidx[ib + lane];
    const int qi = Qidx[ib + lane];
    kposL[wv][lane] = ki;
    qposL[wv][lane] = qi;

    // per-lane both row indices (c32 and 32+c32) via one swap each, no LDS wait
    uint ka = (uint)ki, kb = (uint)ki; plswap(ka, kb);  // ka=kpos[c32], kb=kpos[32+c32]
    uint qa = (uint)qi, qb = (uint)qi; plswap(qa, qb);

    const float* kp0 = Kg + base + (size_t)ka * Dc + dh;
    const float* kp1 = Kg + base + (size_t)kb * Dc + dh;
    const float* qp0 = Qg + base + (size_t)qa * Dc + dh;
    const float* qp1 = Qg + base + (size_t)qb * Dc + dh;

    // ---------- GEMM1: S^T = K * Q^T (bf16x3). Tiles T[mt][nt], mt=K-rows, nt=Q-rows.
    f32x16 T00 = (f32x16)0.f, T01 = (f32x16)0.f, T10 = (f32x16)0.f, T11 = (f32x16)0.f;
    #pragma unroll
    for (int ks = 0; ks < 4; ++ks) {
        FragU kh0, kl0, kh1, kl1, qh0, ql0, qh1, ql1;
        load8split(kp0 + 16 * ks, kh0, kl0);
        load8split(kp1 + 16 * ks, kh1, kl1);
        load8split(qp0 + 16 * ks, qh0, ql0);
        load8split(qp1 + 16 * ks, qh1, ql1);
        T00 = MFMA32(kh0.v, qh0.v, T00); T00 = MFMA32(kh0.v, ql0.v, T00); T00 = MFMA32(kl0.v, qh0.v, T00);
        T01 = MFMA32(kh0.v, qh1.v, T01); T01 = MFMA32(kh0.v, ql1.v, T01); T01 = MFMA32(kl0.v, qh1.v, T01);
        T10 = MFMA32(kh1.v, qh0.v, T10); T10 = MFMA32(kh1.v, ql0.v, T10); T10 = MFMA32(kl1.v, qh0.v, T10);
        T11 = MFMA32(kh1.v, qh1.v, T11); T11 = MFMA32(kh1.v, ql1.v, T11); T11 = MFMA32(kl1.v, qh1.v, T11);
    }

    // ---------- A = exp(S^T) -> bf16 hi/lo A-operand frags, in registers.
    // C/D of tile mt: lane holds col n=c32, rows m_local = 4h+(r&3)+8*(r>>2).
    // A-frag (nt,ks) wants k = 16ks+8h+e; cross-half (h) elements come from the
    // partner lane (lane^32) -> one permlane32_swap per word pair.
    FragU ah[2][4], al[2][4];
    #pragma unroll
    for (int ks = 0; ks < 4; ++ks) {
        const int rb = 8 * (ks & 1);
        #pragma unroll
        for (int nt = 0; nt < 2; ++nt) {
            const f32x16& T = (ks < 2) ? (nt ? T01 : T00) : (nt ? T11 : T10);
            const float a0 = __expf(T[rb + 0]), a1 = __expf(T[rb + 1]);
            const float a2 = __expf(T[rb + 2]), a3 = __expf(T[rb + 3]);
            const float a4 = __expf(T[rb + 4]), a5 = __expf(T[rb + 5]);
            const float a6 = __expf(T[rb + 6]), a7 = __expf(T[rb + 7]);
            FragU H, L;
            split2(a0, a1, H.u[0], L.u[0]);
            split2(a2, a3, H.u[1], L.u[1]);
            split2(a4, a5, H.u[2], L.u[2]);
            split2(a6, a7, H.u[3], L.u[3]);
            plswap(H.u[0], H.u[2]); plswap(H.u[1], H.u[3]);
            plswap(L.u[0], L.u[2]); plswap(L.u[1], L.u[3]);
            ah[nt][ks] = H; al[nt][ks] = L;
        }
    }

    // ---------- GEMM2: R = A * W (bf16x3). W as B-operand via column gathers.
    f32x16 R00 = (f32x16)0.f, R01 = (f32x16)0.f, R10 = (f32x16)0.f, R11 = (f32x16)0.f;
    const float* Wb = Wg + base;
    #pragma unroll
    for (int ks = 0; ks < 4; ++ks) {
        FragU wh0, wl0, wh1, wl1;
        #pragma unroll
        for (int j = 0; j < 4; ++j) {
            const int m0 = 16 * ks + dh + 2 * j;
            const int r0 = kposL[wv][m0];
            const int r1 = kposL[wv][m0 + 1];
            const float* w0 = Wb + (size_t)r0 * Dc + c32;
            const float* w1 = Wb + (size_t)r1 * Dc + c32;
            split2(w0[0],  w1[0],  wh0.u[j], wl0.u[j]);   // vt=0 cols
            split2(w0[32], w1[32], wh1.u[j], wl1.u[j]);   // vt=1 cols
        }
        R00 = MFMA32(ah[0][ks].v, wh0.v, R00); R00 = MFMA32(ah[0][ks].v, wl0.v, R00); R00 = MFMA32(al[0][ks].v, wh0.v, R00);
        R01 = MFMA32(ah[0][ks].v, wh1.v, R01); R01 = MFMA32(ah[0][ks].v, wl1.v, R01); R01 = MFMA32(al[0][ks].v, wh1.v, R01);
        R10 = MFMA32(ah[1][ks].v, wh0.v, R10); R10 = MFMA32(ah[1][ks].v, wl0.v, R10); R10 = MFMA32(al[1][ks].v, wh0.v, R10);
        R11 = MFMA32(ah[1][ks].v, wh1.v, R11); R11 = MFMA32(ah[1][ks].v, wl1.v, R11); R11 = MFMA32(al[1][ks].v, wh1.v, R11);
    }

    // ---------- scatter store: row n -> out[qpos[n]], cols split vt=0/1.
    float* Ob = Og + base;
    #pragma unroll
    for (int nt = 0; nt < 2; ++nt) {
        const f32x16& Ra = nt ? R10 : R00;
        const f32x16& Rb = nt ? R11 : R01;
        #pragma unroll
        for (int r = 0; r < 16; ++r) {
            const int n    = 32 * nt + 4 * h + (r & 3) + 8 * (r >> 2);
            const int orow = qposL[wv][n];
            float* po = Ob + (size_t)orow * Dc;
            po[c32]      = Ra[r];
            po[32 + c32] = Rb[r];
        }
    }
}

extern "C" void kernel_launch(void* const* d_in, const int* in_sizes, int n_in,
                              void* d_out, int out_size, void* d_ws, size_t ws_size,
                              hipStream_t stream) {
    const float* query  = (const float*)d_in[0];
    const float* key    = (const float*)d_in[1];
    const float* weight = (const float*)d_in[2];
    const int*   kidx   = (const int*)d_in[3];
    const int*   qidx   = (const int*)d_in[4];
    float*       out    = (float*)d_out;

    const int BH     = in_sizes[3] / Nc;           // 64
    const int nbuck  = BH * (Nc / 64);             // 4096
    const int blocks = (nbuck + WPB - 1) / WPB;    // 1024
    lsh_mfma3<<<blocks, WPB * 64, 0, stream>>>(query, key, weight, kidx, qidx, out, nbuck);
}